// Round 9
// baseline (182.931 us; speedup 1.0000x reference)
//
#include <hip/hip_runtime.h>
#include <math.h>

#define PS   65
#define NPIX (PS * PS)
#define S1   789               // S slot stride (odd, 21 mod 32: spreads banks)
#define NTH  320

// atan(t)*(4/pi) for t in [0,1], degree-9 odd minimax, |err|<=1.3e-5
#define C0  1.2730689f
#define C1 -0.4205505f
#define C2  0.2293627f
#define C3 -0.1083947f
#define C4  0.0265281f

// triangular pooling weight, compile-time
__host__ __device__ constexpr float triwc(int t) {
    float d = (float)t - 12.5f;
    d = d < 0.0f ? -d : d;
    return (13.0f - d) / 13.0f;
}

__global__ __launch_bounds__(NTH) void sift_desc_kernel(
        const float* __restrict__ img, float* __restrict__ out) {
    const int s   = blockIdx.x;     // slice index in (B, C, 8, 8) row-major
    const int tid = threadIdx.x;

    // decode slice -> (b, c, tile_i, tile_j)
    const int b   = s / 192;        // C*8*8 = 192
    const int rem = s - b * 192;
    const int c   = rem >> 6;
    const int t2  = rem & 63;
    const int pi  = t2 >> 3;
    const int pj  = t2 & 7;
    const float* src = img + ((size_t)((b * 3 + c) * 520 + pi * 65)) * 520 + pj * 65;

    __shared__ float patch[NPIX];   // 65x65 tile (pitch 65 -> 2-way banks max)
    __shared__ float S[8 * S1];     // rings: S[slot*S1 + 3*(4y+q) + plane]
    __shared__ float gtab[PS];      // normalized gaussian * sqrt(0.5)
    __shared__ float fin[128];
    __shared__ float redv[2];

    // phase 0: gaussian table + stage patch (no S zeroing needed: every read
    // location is written unconditionally by exactly one thread)
    if (tid < PS) {
        float d = (float)(tid - 32);
        gtab[tid] = expf(-(d * d) * (1.0f / 4225.0f));  // sigma=65/sqrt2 -> 2s^2=4225
    }
    for (int p = tid; p < NPIX; p += NTH) {
        int y = p / 65;
        int x = p - y * 65;
        patch[p] = src[y * 520 + x];
    }
    __syncthreads();

    // normalize gtab; fold sqrt(0.5) (the two 0.5 gradient factors, one per axis)
    if (tid < 64) {
        float v = gtab[tid] + ((tid == 0) ? gtab[64] : 0.0f);
        #pragma unroll
        for (int off = 32; off > 0; off >>= 1) v += __shfl_down(v, off);
        if (tid == 0) redv[0] = 0.70710678f / v;
    }
    __syncthreads();
    const float invZ = redv[0];
    if (tid < PS) gtab[tid] *= invZ;
    __syncthreads();

    // ---- fused pass: item = (row y, quarter q). All histogram accumulation in
    // REGISTERS (24 accs: windows q-1, q, q+1); NO LDS RMW anywhere.
    if (tid < 260) {
        const int y  = tid >> 2;
        const int q  = tid & 3;
        const int x0 = q << 4;

        const int rowb = y * 65;
        const int rowm = (y > 0  ? y - 1 : 0)  * 65;
        const int rowp = (y < 64 ? y + 1 : 64) * 65;
        const float gy_t = gtab[y];

        float accB[8] = {0,0,0,0,0,0,0,0};   // window q-1 (px i=0..3, t=i+22)
        float accQ[8] = {0,0,0,0,0,0,0,0};   // window q   (all px, t=i+6)
        float accP[8] = {0,0,0,0,0,0,0,0};   // window q+1 (px i=10..15, t=i-10)

        float cprev = patch[rowb + ((q == 0) ? 0 : x0 - 1)];
        float ccur  = patch[rowb + x0];

#define PX_MATH(XEXPR, CNEXT_EXPR)                                             \
            const int x  = (XEXPR);                                            \
            float cnext = (CNEXT_EXPR);                                        \
            float top = patch[rowm + x];                                       \
            float bot = patch[rowp + x];                                       \
            float G = cnext - cprev;            /* 2*gx */                     \
            float H = bot - top;                /* 2*gy */                     \
            float mag = sqrtf(fmaf(G, G, fmaf(H, H, 4e-10f))) * (gy_t * gtab[x]); \
            float Gx = G + 2e-10f;                                             \
            float ax = fabsf(Gx), ay = fabsf(H);                               \
            float mn = fminf(ax, ay), mx = fmaxf(ax, ay);                      \
            float t1 = mn * __builtin_amdgcn_rcpf(fmaxf(mx, 1e-35f));          \
            float ss = t1 * t1;                                                \
            float u9 = t1 * fmaf(ss, fmaf(ss, fmaf(ss, fmaf(ss, C4, C3), C2), C1), C0); \
            float A  = (ay > ax) ? 2.0f - u9 : u9;                             \
            A = (Gx < 0.0f) ? 4.0f - A : A;                                    \
            A = (H  < 0.0f) ? -A : A;                                          \
            float ob = A + 8.0f;                /* in [4,12] */                \
            float fl = truncf(ob);                                             \
            float fr = ob - fl;                                                \
            int b0 = ((int)fl) & 7;                                            \
            float w1 = fr * mag;                                               \
            float w0 = mag - w1;                                               \
            float sarr[8];                                                     \
            _Pragma("unroll")                                                  \
            for (int k = 0; k < 8; ++k) {                                      \
                const int km1 = (k + 7) & 7;                                   \
                float sv = (b0 == k) ? w0 : 0.0f;                              \
                sarr[k] = (b0 == km1) ? w1 : sv;                               \
            }                                                                  \
            cprev = ccur; ccur = cnext;

        #pragma unroll
        for (int i = 0; i < 16; ++i) {
            PX_MATH(x0 + i, patch[rowb + x + 1])
            const float WA = triwc(i + 6);
            #pragma unroll
            for (int k = 0; k < 8; ++k) accQ[k] = fmaf(sarr[k], WA, accQ[k]);
            if (i < 4) {
                const float WB = triwc(i + 22);
                #pragma unroll
                for (int k = 0; k < 8; ++k) accB[k] = fmaf(sarr[k], WB, accB[k]);
            }
            if (i >= 10) {
                const float WP = triwc(i - 10);
                #pragma unroll
                for (int k = 0; k < 8; ++k) accP[k] = fmaf(sarr[k], WP, accP[k]);
            }
        }
        if (q == 3) {   // 17th pixel x=64: only window q=3 (t=22)
            PX_MATH(64, ccur)
            const float WA = triwc(22);
            #pragma unroll
            for (int k = 0; k < 8; ++k) accQ[k] = fmaf(sarr[k], WA, accQ[k]);
        }
#undef PX_MATH

        // plain stores, each (slot, ring) written by exactly one thread.
        // bank = (21*slot + 3*tid + p) mod 32 -> 2-way (free) per instruction.
        const int wb = 3 * tid;
        #pragma unroll
        for (int k = 0; k < 8; ++k) {
            S[k * S1 + wb + 0] = accB[k];
            S[k * S1 + wb + 1] = accQ[k];
            S[k * S1 + wb + 2] = accP[k];
        }
    }
    __syncthreads();

    // ---- row pass: window j of row y has 3 writers: (q=j+1, plane0),
    // (q=j, plane1), (q=j-1, plane2). Edge windows mask the missing source.
    if (tid < 128) {
        const int k  = tid >> 4;          // angular bin
        const int ii = (tid >> 2) & 3;    // y-window
        const int j  = tid & 3;           // x-window
        const int qA = (j < 3) ? j + 1 : 3;
        const int qC = (j > 0) ? j - 1 : 0;
        const float fA = (j < 3) ? 1.0f : 0.0f;
        const float fC = (j > 0) ? 1.0f : 0.0f;
        float sA = 0.0f, sB = 0.0f, sC = 0.0f;
        #pragma unroll
        for (int t = 0; t < 26; ++t) {
            const int y  = 16 * ii + t - 6;
            const int yc = (y < 0) ? 0 : ((y > 64) ? 64 : y);
            const float wy = (y == yc) ? triwc(t) : 0.0f;
            const int base = k * S1 + 12 * yc;
            sA = fmaf(wy, S[base + 3 * qA + 0], sA);
            sB = fmaf(wy, S[base + 3 * j  + 1], sB);
            sC = fmaf(wy, S[base + 3 * qC + 2], sC);
        }
        fin[tid] = fmaf(fA, sA, fmaf(fC, sC, sB));
    }
    __syncthreads();

    // first L2 norm
    if (tid < 64) {
        float sq = fin[tid] * fin[tid] + fin[tid + 64] * fin[tid + 64];
        #pragma unroll
        for (int off = 32; off > 0; off >>= 1) sq += __shfl_down(sq, off);
        if (tid == 0) redv[0] = sq;
    }
    __syncthreads();
    float inv1 = 1.0f / fmaxf(sqrtf(redv[0]), 1e-12f);
    if (tid < 128) {
        fin[tid] = fminf(fin[tid] * inv1, 0.2f);   // non-negative; clip hi only
    }
    __syncthreads();

    // second L2 norm
    if (tid < 64) {
        float sq = fin[tid] * fin[tid] + fin[tid + 64] * fin[tid + 64];
        #pragma unroll
        for (int off = 32; off > 0; off >>= 1) sq += __shfl_down(sq, off);
        if (tid == 0) redv[1] = sq;
    }
    __syncthreads();
    float inv2 = 1.0f / fmaxf(sqrtf(redv[1]), 1e-12f);
    if (tid < 128) {
        out[(size_t)s * 128 + tid] = fin[tid] * inv2;
    }
}

extern "C" void kernel_launch(void* const* d_in, const int* in_sizes, int n_in,
                              void* d_out, int out_size, void* d_ws, size_t ws_size,
                              hipStream_t stream) {
    const float* img = (const float*)d_in[0];
    float* out = (float*)d_out;
    const int B = in_sizes[0] / (3 * 520 * 520);
    const int nslices = B * 192;
    sift_desc_kernel<<<nslices, NTH, 0, stream>>>(img, out);
}

// Round 10
// 178.934 us; speedup vs baseline: 1.0223x; 1.0223x over previous
//
#include <hip/hip_runtime.h>
#include <math.h>

#define PS    65
#define PP    68                 // patch pitch: rows 16B-aligned (272B), cols 0..64 used
#define NTH   320

// atan(t)*(4/pi) for t in [0,1], degree-9 odd minimax, |err|<=1.3e-5
#define C0  1.2730689f
#define C1 -0.4205505f
#define C2  0.2293627f
#define C3 -0.1083947f
#define C4  0.0265281f

// triangular pooling weight, compile-time
__host__ __device__ constexpr float triwc(int t) {
    float d = (float)t - 12.5f;
    d = d < 0.0f ? -d : d;
    return (13.0f - d) / 13.0f;
}

__global__ __launch_bounds__(NTH) void sift_desc_kernel(
        const float* __restrict__ img, float* __restrict__ out) {
    const int s   = blockIdx.x;     // slice index in (B, C, 8, 8) row-major
    const int tid = threadIdx.x;

    // decode slice -> (b, c, tile_i, tile_j)
    const int b   = s / 192;        // C*8*8 = 192
    const int rem = s - b * 192;
    const int c   = rem >> 6;
    const int t2  = rem & 63;
    const int pi  = t2 >> 3;
    const int pj  = t2 & 7;
    const float* src = img + ((size_t)((b * 3 + c) * 520 + pi * 65)) * 520 + pj * 65;

    __shared__ __align__(16) float patch[PS * PP];  // 17.7 KB; aliased as fin later
    __shared__ __align__(16) float S[2080];         // W[y][j][k] = S[(4y+j)*8+k], 8.3 KB
    __shared__ __align__(16) float gtab[PP];        // normalized gaussian * sqrt(0.5)
    __shared__ float redv[4];

    float* fin = patch;   // patch is dead after the fused pass (barrier-separated)

    // phase 0: gaussian + stage patch (pitch 68)
    if (tid < PS) {
        float d = (float)(tid - 32);
        gtab[tid] = expf(-(d * d) * (1.0f / 4225.0f));  // sigma=65/sqrt2 -> 2s^2=4225
    }
    for (int p = tid; p < PS * PS; p += NTH) {
        int y = p / 65;
        int x = p - y * 65;
        patch[y * PP + x] = src[y * 520 + x];
    }
    __syncthreads();

    // normalize gtab; fold sqrt(0.5) (the two 0.5 gradient factors, one per axis)
    if (tid < 64) {
        float v = gtab[tid] + ((tid == 0) ? gtab[64] : 0.0f);
        #pragma unroll
        for (int off = 32; off > 0; off >>= 1) v += __shfl_down(v, off);
        if (tid == 0) redv[0] = 0.70710678f / v;
    }
    __syncthreads();
    const float invZ = redv[0];
    if (tid < PS) gtab[tid] *= invZ;
    __syncthreads();

    // ---- fused pass: item = (row y, quarter q), tid = 4y+q. Bulk-load the 3 rows
    // + gtab to registers (13x ds_read_b128), then pure-VALU 16/17-px loop with
    // 24 register accumulators. Neighbor-window merge via shfl; 2 b128 stores.
    if (tid < 260) {
        const int y  = tid >> 2;
        const int q  = tid & 3;
        const int x0 = q << 4;
        const int rowb = y * PP;
        const int rowm = (y > 0  ? y - 1 : 0)  * PP;
        const int rowp = (y < 64 ? y + 1 : 64) * PP;
        const float gy_t = gtab[y];

        float4 Cv[4], Tv[4], Bv[4], Gv[4];
        #pragma unroll
        for (int g = 0; g < 4; ++g) {
            Cv[g] = *(const float4*)&patch[rowb + x0 + 4 * g];
            Tv[g] = *(const float4*)&patch[rowm + x0 + 4 * g];
            Bv[g] = *(const float4*)&patch[rowp + x0 + 4 * g];
            Gv[g] = *(const float4*)&gtab[x0 + 4 * g];
        }
        const float cm1 = patch[rowb + ((q == 0) ? 0 : x0 - 1)];
        const float c16 = patch[rowb + x0 + 16];   // x0+16 <= 64 always
        const float t16 = patch[rowm + x0 + 16];
        const float b16 = patch[rowp + x0 + 16];
        const float g16 = gtab[x0 + 16];

        const float Ca[17] = {Cv[0].x,Cv[0].y,Cv[0].z,Cv[0].w, Cv[1].x,Cv[1].y,Cv[1].z,Cv[1].w,
                              Cv[2].x,Cv[2].y,Cv[2].z,Cv[2].w, Cv[3].x,Cv[3].y,Cv[3].z,Cv[3].w, c16};
        const float Ta[16] = {Tv[0].x,Tv[0].y,Tv[0].z,Tv[0].w, Tv[1].x,Tv[1].y,Tv[1].z,Tv[1].w,
                              Tv[2].x,Tv[2].y,Tv[2].z,Tv[2].w, Tv[3].x,Tv[3].y,Tv[3].z,Tv[3].w};
        const float Ba[16] = {Bv[0].x,Bv[0].y,Bv[0].z,Bv[0].w, Bv[1].x,Bv[1].y,Bv[1].z,Bv[1].w,
                              Bv[2].x,Bv[2].y,Bv[2].z,Bv[2].w, Bv[3].x,Bv[3].y,Bv[3].z,Bv[3].w};
        const float Ga[16] = {Gv[0].x,Gv[0].y,Gv[0].z,Gv[0].w, Gv[1].x,Gv[1].y,Gv[1].z,Gv[1].w,
                              Gv[2].x,Gv[2].y,Gv[2].z,Gv[2].w, Gv[3].x,Gv[3].y,Gv[3].z,Gv[3].w};

        float accB[8] = {0,0,0,0,0,0,0,0};   // window q-1 (px i=0..3,  t=i+22)
        float accQ[8] = {0,0,0,0,0,0,0,0};   // window q   (all px,     t=i+6)
        float accP[8] = {0,0,0,0,0,0,0,0};   // window q+1 (px i=10..15,t=i-10)

        auto PX = [&](float cp, float cn, float tp, float bt, float gx_t,
                      float (&sarr)[8]) {
            float G = cn - cp;                  // 2*gx
            float H = bt - tp;                  // 2*gy
            float mag = sqrtf(fmaf(G, G, fmaf(H, H, 4e-10f))) * (gy_t * gx_t);
            float Gx = G + 2e-10f;
            float ax = fabsf(Gx), ay = fabsf(H);
            float mn = fminf(ax, ay), mx = fmaxf(ax, ay);
            float t1 = mn * __builtin_amdgcn_rcpf(fmaxf(mx, 1e-35f));
            float ss = t1 * t1;
            float u9 = t1 * fmaf(ss, fmaf(ss, fmaf(ss, fmaf(ss, C4, C3), C2), C1), C0);
            float A  = (ay > ax) ? 2.0f - u9 : u9;
            A = (Gx < 0.0f) ? 4.0f - A : A;
            A = (H  < 0.0f) ? -A : A;
            float ob = A + 8.0f;                // in [4,12]
            float fl = truncf(ob);
            float fr = ob - fl;
            int b0 = ((int)fl) & 7;
            float w1 = fr * mag;
            float w0 = mag - w1;
            #pragma unroll
            for (int k = 0; k < 8; ++k) {
                const int km1 = (k + 7) & 7;
                float sv = (b0 == k) ? w0 : 0.0f;
                sarr[k] = (b0 == km1) ? w1 : sv;
            }
        };

        #pragma unroll
        for (int i = 0; i < 16; ++i) {
            float sarr[8];
            PX((i == 0) ? cm1 : Ca[i - 1], Ca[i + 1], Ta[i], Ba[i], Ga[i], sarr);
            const float WA = triwc(i + 6);
            #pragma unroll
            for (int k = 0; k < 8; ++k) accQ[k] = fmaf(sarr[k], WA, accQ[k]);
            if (i < 4) {
                const float WB = triwc(i + 22);
                #pragma unroll
                for (int k = 0; k < 8; ++k) accB[k] = fmaf(sarr[k], WB, accB[k]);
            }
            if (i >= 10) {
                const float WP = triwc(i - 10);
                #pragma unroll
                for (int k = 0; k < 8; ++k) accP[k] = fmaf(sarr[k], WP, accP[k]);
            }
        }
        if (q == 3) {   // 17th pixel x=64 (t=22, own window only); cnext clamps to self
            float sarr[8];
            PX(Ca[15], c16, t16, b16, g16, sarr);
            const float WA = triwc(22);
            #pragma unroll
            for (int k = 0; k < 8; ++k) accQ[k] = fmaf(sarr[k], WA, accQ[k]);
        }

        // merge neighbor windows via shfl (lane groups of 4 never straddle a wave)
        const float fB = (q < 3) ? 1.0f : 0.0f;
        const float fP = (q > 0) ? 1.0f : 0.0f;
        float wk[8];
        #pragma unroll
        for (int k = 0; k < 8; ++k) {
            float nb = __shfl_down(accB[k], 1);   // from q+1: its window q
            float np = __shfl_up(accP[k], 1);     // from q-1: its window q
            wk[k] = accQ[k] + fB * nb + fP * np;
        }
        *(float4*)&S[tid * 8]     = make_float4(wk[0], wk[1], wk[2], wk[3]);
        *(float4*)&S[tid * 8 + 4] = make_float4(wk[4], wk[5], wk[6], wk[7]);
    }
    __syncthreads();

    // ---- row pass: bin = k*16 + ii*4 + j sums W[y][j][k] with triangular wy
    if (tid < 128) {
        const int k  = tid >> 4;
        const int ii = (tid >> 2) & 3;
        const int j  = tid & 3;
        float v = 0.0f;
        #pragma unroll
        for (int t = 0; t < 26; ++t) {
            const int y  = 16 * ii + t - 6;
            const int yc = (y < 0) ? 0 : ((y > 64) ? 64 : y);
            const float wy = (y == yc) ? triwc(t) : 0.0f;
            v = fmaf(wy, S[((yc << 2) + j) * 8 + k], v);
        }
        fin[tid] = v;   // fin aliases patch (dead), safe post-barrier
    }
    __syncthreads();

    // first L2 norm
    if (tid < 64) {
        float sq = fin[tid] * fin[tid] + fin[tid + 64] * fin[tid + 64];
        #pragma unroll
        for (int off = 32; off > 0; off >>= 1) sq += __shfl_down(sq, off);
        if (tid == 0) redv[1] = sq;
    }
    __syncthreads();
    float inv1 = 1.0f / fmaxf(sqrtf(redv[1]), 1e-12f);
    if (tid < 128) {
        fin[tid] = fminf(fin[tid] * inv1, 0.2f);   // non-negative; clip hi only
    }
    __syncthreads();

    // second L2 norm
    if (tid < 64) {
        float sq = fin[tid] * fin[tid] + fin[tid + 64] * fin[tid + 64];
        #pragma unroll
        for (int off = 32; off > 0; off >>= 1) sq += __shfl_down(sq, off);
        if (tid == 0) redv[2] = sq;
    }
    __syncthreads();
    float inv2 = 1.0f / fmaxf(sqrtf(redv[2]), 1e-12f);
    if (tid < 128) {
        out[(size_t)s * 128 + tid] = fin[tid] * inv2;
    }
}

extern "C" void kernel_launch(void* const* d_in, const int* in_sizes, int n_in,
                              void* d_out, int out_size, void* d_ws, size_t ws_size,
                              hipStream_t stream) {
    const float* img = (const float*)d_in[0];
    float* out = (float*)d_out;
    const int B = in_sizes[0] / (3 * 520 * 520);
    const int nslices = B * 192;
    sift_desc_kernel<<<nslices, NTH, 0, stream>>>(img, out);
}